// Round 8
// baseline (518.621 us; speedup 1.0000x reference)
//
#include <hip/hip_runtime.h>
#include <hip/hip_cooperative_groups.h>
#include <math.h>

namespace cg = cooperative_groups;

#define BATCH 128
#define CIN 3
#define H 224
#define W 224
#define C1 16
#define HP 56
#define WP 56
#define C2 32
#define H2 28
#define W2 28

#define TROWS 17               // input rows per conv1 strip (4 pooled rows + halo)
#define CHF (TROWS * W)        // 3808 floats per channel chunk
#define CHB (CHF * 4)          // 15232 bytes per channel chunk

// ---------------------------------------------------------------------------
// R13: SINGLE cooperative kernel. Cross-round e2e-vs-dispatch arithmetic says
// real kernel work is ~50us inside a ~220us e2e -> per-operation launch/graph
// overhead (~40us x 4 ops) dominates. Fuse all 4 ops into 1:
//   phase 0: zero stats (in-kernel, replaces hipMemsetAsync)
//   phase 1: conv1+pool+bn1-stats (R11 body, grid-strided over 1792 strips)
//   phase 2: conv2+bn2-stats      (R9 body, grid-strided over 784 units)
//   phase 3: head (BN2+ReLU+avgpool+FC+cos, blocks 0..127)
// grid.sync() + __threadfence() between phases: threadfence = agent-scope
// fence (L2 writeback on release / invalidate on acquire) -> mm/y2 handoff
// is correct across non-coherent per-XCD L2s; stats zero+accumulate stay on
// the device-scope atomic path. Readers never cache peers' regions before
// the sync, so release-writeback + acquire-invalidate suffices.
// Grid = occupancy-query blocks/CU x 256 CUs (expect 3/CU -> 768), so
// cooperative co-residency is guaranteed by construction.
// ---------------------------------------------------------------------------
__global__ __launch_bounds__(256) void fused_all_k(
    const float* __restrict__ x, const float* __restrict__ w1,
    const float* __restrict__ b1, const float* __restrict__ g1,
    const float* __restrict__ be1, const float* __restrict__ w2,
    const float* __restrict__ b2, const float* __restrict__ g2,
    const float* __restrict__ be2, const float* __restrict__ fcw,
    const float* __restrict__ fcb, float2* __restrict__ mm,
    float* __restrict__ y2, float* __restrict__ stats,
    float* __restrict__ out)
{
    cg::grid_group grid = cg::this_grid();
    __shared__ __align__(16) float tile[3 * CHF];   // 45,696 B (phase 1)
    __shared__ float red[4][16], redq[4][16];       // reused by phases 1,2
    __shared__ float feat[C2];                      // phase 3

    float* s1sum = stats;          // 16
    float* s1sq  = stats + 16;     // 16
    float* s2sum = stats + 32;     // 32
    float* s2sq  = stats + 64;     // 32

    const int tid = threadIdx.x;
    const int wave = tid >> 6, lane = tid & 63;

    // ---- phase 0: zero stats accumulators ----
    if (blockIdx.x == 0 && tid < 96) stats[tid] = 0.0f;
    __threadfence();
    grid.sync();
    __threadfence();

    // ---- phase 1: conv1 (s2,p1) + 2x2 pool(max,min) + bn1 stats ----
    for (int u = blockIdx.x; u < 1792; u += gridDim.x) {
        const int n = u / 14;
        const int g = u % 14;                 // pooled-row group (4 rows)
        const int ph = g * 4 + wave;          // this wave's pooled row
        const int pw = (lane < 56) ? lane : 55;
        const bool active = lane < 56;
        const bool topok = ph > 0;
        const bool pwok  = pw > 0;

        // fill: async global->LDS, 16B/lane, wave-uniform dest (R11-proven)
        const int startrow = (g == 0) ? 0 : (16 * g - 1);
        const int nops     = (g == 0) ? 14 : 15;      // 1024B ops per channel
        const int base_off = (g == 0) ? (W * 4) : 0;  // row -1 slot skipped
#pragma unroll
        for (int ci = 0; ci < CIN; ++ci) {
            const char* gch = (const char*)(x + ((size_t)n * CIN + ci) * (H * W)
                                            + (size_t)startrow * W);
            char* lch = (char*)tile + ci * CHB + base_off;
            for (int kp = wave; kp < nops; kp += 4) {
                int off = kp * 1024;
                if (off > 14208) off = 14208;   // exact-coverage clamp
                __builtin_amdgcn_global_load_lds(
                    (const __attribute__((address_space(1))) void*)(gch + off + lane * 16),
                    (__attribute__((address_space(3))) void*)(lch + off),
                    16, 0, 0);
            }
        }

        float acc[16][4];
#pragma unroll
        for (int j = 0; j < 16; ++j) {
            const float bb = b1[j];
#pragma unroll
            for (int q = 0; q < 4; ++q) acc[j][q] = bb;
        }

        __syncthreads();   // drains vmcnt(0): all LDS writes landed

#pragma unroll
        for (int ci = 0; ci < CIN; ++ci) {
#pragma unroll
            for (int l = 0; l < 5; ++l) {
                const int tr = 4 * wave + l;    // tile row (0..16)
                const float* rp = tile + ci * CHF + tr * W;
                const float4 fa = *(const float4*)(rp + 4 * pw);
                const float4 fb = *(const float4*)(rp + max(4 * pw - 4, 0));
                const bool rok = (l > 0) || topok;
                const float p0 = (rok && pwok) ? fb.w : 0.0f;
                const float p1 = rok ? fa.x : 0.0f;
                const float p2 = rok ? fa.y : 0.0f;
                const float p3 = rok ? fa.z : 0.0f;
                const float p4 = rok ? fa.w : 0.0f;
#pragma unroll
                for (int j = 0; j < 16; ++j) {
                    const float* wc = w1 + (j * CIN + ci) * 9;
                    if (l < 3) {
                        const float wa = wc[l * 3 + 0];
                        const float wb = wc[l * 3 + 1];
                        const float wd = wc[l * 3 + 2];
                        acc[j][0] += wa * p0 + wb * p1 + wd * p2;
                        acc[j][1] += wa * p2 + wb * p3 + wd * p4;
                    }
                    if (l >= 2) {
                        const int kh = l - 2;
                        const float wa = wc[kh * 3 + 0];
                        const float wb = wc[kh * 3 + 1];
                        const float wd = wc[kh * 3 + 2];
                        acc[j][2] += wa * p0 + wb * p1 + wd * p2;
                        acc[j][3] += wa * p2 + wb * p3 + wd * p4;
                    }
                }
            }
        }

#pragma unroll
        for (int j = 0; j < 16; ++j) {
            const float a0 = acc[j][0], a1 = acc[j][1], a2 = acc[j][2], a3 = acc[j][3];
            if (active) {
                const int o = (n * C1 + j) * (HP * WP) + ph * WP + pw;
                mm[o] = make_float2(fmaxf(fmaxf(a0, a1), fmaxf(a2, a3)),
                                    fminf(fminf(a0, a1), fminf(a2, a3)));
            }
            float s = active ? (a0 + a1 + a2 + a3) : 0.0f;
            float q = active ? (a0 * a0 + a1 * a1 + a2 * a2 + a3 * a3) : 0.0f;
#pragma unroll
            for (int off = 32; off > 0; off >>= 1) {
                s += __shfl_xor(s, off);
                q += __shfl_xor(q, off);
            }
            if (lane == 0) { red[wave][j] = s; redq[wave][j] = q; }
        }
        __syncthreads();   // also orders: tile reads done before next fill
        if (tid < 16) {
            atomicAdd(&s1sum[tid],
                      red[0][tid] + red[1][tid] + red[2][tid] + red[3][tid]);
        } else if (tid < 32) {
            const int j = tid - 16;
            atomicAdd(&s1sq[j],
                      redq[0][j] + redq[1][j] + redq[2][j] + redq[3][j]);
        }
    }

    __threadfence();       // release: write back mm + stats from this XCD's L2
    grid.sync();
    __threadfence();       // acquire: invalidate stale lines before reading

    // ---- phase 2: conv2 (s2,p1) + bn2 stats (BN1 finalize folded) ----
    {
        const float inv1 = 1.0f / (float)(BATCH * 112 * 112);
        for (int v = blockIdx.x; v < 784; v += gridDim.x) {
            const int bx = v % 196, by = v / 196;
            const int t = bx * 256 + tid;   // 0..50175
            const int c0 = by * 8;
            const int n = t / 392;
            const int r = t % 392;          // 28 rows x 14 col-pairs
            const int oh = r / 14;
            const int ow = (r % 14) * 2;    // even; outputs ow, ow+1
            const bool topok = oh > 0;
            const bool owok  = ow > 0;

            float accA[8], accB[8];
#pragma unroll
            for (int c = 0; c < 8; ++c) { accA[c] = b2[c0 + c]; accB[c] = accA[c]; }

#pragma unroll 2
            for (int ci = 0; ci < C1; ++ci) {
                const float mean = s1sum[ci] * inv1;
                const float var  = s1sq[ci] * inv1 - mean * mean;
                const float s1 = g1[ci] * rsqrtf(var + 1e-5f);
                const float t1 = be1[ci] - mean * s1;

                const float2* pl = mm + (n * C1 + ci) * (HP * WP);

                float4 fa[3], fb[3];
                float2 lpv[3];
#pragma unroll
                for (int kh = 0; kh < 3; ++kh) {
                    const int ih = max(2 * oh - 1 + kh, 0);
                    const float2* rowp = pl + ih * WP;
                    fa[kh]  = *(const float4*)(rowp + 2 * ow);
                    fb[kh]  = *(const float4*)(rowp + 2 * ow + 2);
                    lpv[kh] = rowp[max(2 * ow - 1, 0)];
                }

                float h[3][5];
#pragma unroll
                for (int kh = 0; kh < 3; ++kh) {
                    const bool rok = (kh > 0) || topok;
                    const float u0 = fmaxf(0.0f, fmaxf(s1 * lpv[kh].x + t1, s1 * lpv[kh].y + t1));
                    const float u1 = fmaxf(0.0f, fmaxf(s1 * fa[kh].x + t1, s1 * fa[kh].y + t1));
                    const float u2 = fmaxf(0.0f, fmaxf(s1 * fa[kh].z + t1, s1 * fa[kh].w + t1));
                    const float u3 = fmaxf(0.0f, fmaxf(s1 * fb[kh].x + t1, s1 * fb[kh].y + t1));
                    const float u4 = fmaxf(0.0f, fmaxf(s1 * fb[kh].z + t1, s1 * fb[kh].w + t1));
                    h[kh][0] = (rok && owok) ? u0 : 0.0f;
                    h[kh][1] = rok ? u1 : 0.0f;
                    h[kh][2] = rok ? u2 : 0.0f;
                    h[kh][3] = rok ? u3 : 0.0f;
                    h[kh][4] = rok ? u4 : 0.0f;
                }

#pragma unroll
                for (int c = 0; c < 8; ++c) {
                    const float* wc = w2 + ((c0 + c) * C1 + ci) * 9;
                    float a = accA[c], b = accB[c];
#pragma unroll
                    for (int kh = 0; kh < 3; ++kh) {
                        const float w0 = wc[kh * 3 + 0];
                        const float w1v = wc[kh * 3 + 1];
                        const float w2v = wc[kh * 3 + 2];
                        a += w0 * h[kh][0] + w1v * h[kh][1] + w2v * h[kh][2];
                        b += w0 * h[kh][2] + w1v * h[kh][3] + w2v * h[kh][4];
                    }
                    accA[c] = a; accB[c] = b;
                }
            }

#pragma unroll
            for (int c = 0; c < 8; ++c) {
                const float aA = accA[c], aB = accB[c];
                const int p = oh * W2 + ow;
                *(float2*)(y2 + (n * C2 + c0 + c) * (H2 * W2) + p) = make_float2(aA, aB);
                float s = aA + aB, q = aA * aA + aB * aB;
#pragma unroll
                for (int off = 32; off > 0; off >>= 1) {
                    s += __shfl_xor(s, off);
                    q += __shfl_xor(q, off);
                }
                if ((tid & 63) == 0) { red[tid >> 6][c] = s; redq[tid >> 6][c] = q; }
            }
            __syncthreads();
            if (tid < 8) {
                atomicAdd(&s2sum[c0 + tid],
                          red[0][tid] + red[1][tid] + red[2][tid] + red[3][tid]);
            } else if (tid < 16) {
                const int c = tid - 8;
                atomicAdd(&s2sq[c0 + c],
                          redq[0][c] + redq[1][c] + redq[2][c] + redq[3][c]);
            }
            __syncthreads();   // red reuse across v-iterations
        }
    }

    __threadfence();
    grid.sync();
    __threadfence();

    // ---- phase 3: head (BN2 finalize + ReLU + avgpool + FC + cos) ----
    for (int n = blockIdx.x; n < BATCH; n += gridDim.x) {
        const float inv2 = 1.0f / (float)(BATCH * H2 * W2);
#pragma unroll
        for (int k = 0; k < 8; ++k) {
            const int c = wave * 8 + k;
            const float mean = s2sum[c] * inv2;
            const float var  = s2sq[c] * inv2 - mean * mean;
            const float s = g2[c] * rsqrtf(var + 1e-5f);
            const float t = be2[c] - mean * s;
            const float4* yp = (const float4*)(y2 + (n * C2 + c) * (H2 * W2));
            float a = 0.0f;
            for (int i = lane; i < 196; i += 64) {
                const float4 v = yp[i];
                a += fmaxf(0.0f, s * v.x + t) + fmaxf(0.0f, s * v.y + t)
                   + fmaxf(0.0f, s * v.z + t) + fmaxf(0.0f, s * v.w + t);
            }
#pragma unroll
            for (int off = 32; off > 0; off >>= 1) a += __shfl_xor(a, off);
            if (lane == 0) feat[c] = a * (1.0f / (H2 * W2));
        }
        __syncthreads();
        if (tid == 0) {
            float logit = fcb[0];
#pragma unroll
            for (int c = 0; c < C2; ++c) logit += feat[c] * fcw[c];
            const float pc = cosf(logit);
            out[2 * n]     = pc;
            out[2 * n + 1] = 1.0f - pc;
        }
        __syncthreads();
    }
}

extern "C" void kernel_launch(void* const* d_in, const int* in_sizes, int n_in,
                              void* d_out, int out_size, void* d_ws, size_t ws_size,
                              hipStream_t stream) {
    const float* x   = (const float*)d_in[0];
    const float* w1  = (const float*)d_in[1];
    const float* b1  = (const float*)d_in[2];
    const float* g1  = (const float*)d_in[3];
    const float* be1 = (const float*)d_in[4];
    const float* w2  = (const float*)d_in[5];
    const float* b2  = (const float*)d_in[6];
    const float* g2  = (const float*)d_in[7];
    const float* be2 = (const float*)d_in[8];
    const float* fcw = (const float*)d_in[9];
    const float* fcb = (const float*)d_in[10];
    float* out = (float*)d_out;

    float* ws = (float*)d_ws;
    float2* mm = (float2*)ws;                              // 6,422,528 float2
    float* y2 = ws + (size_t)2 * BATCH * C1 * HP * WP;     // 3,211,264 floats
    float* stats = y2 + (size_t)BATCH * C2 * H2 * W2;      // 96 floats
    // ws use ~64.3 MB (proven safe)

    // Cooperative grid: occupancy-derived so co-residency is guaranteed.
    // Expect 3 blocks/CU (LDS 46.6KB) x 256 CUs = 768.
    static int g_grid = 0;
    if (g_grid == 0) {
        int nb = 0;
        hipError_t e = hipOccupancyMaxActiveBlocksPerMultiprocessor(
            &nb, fused_all_k, 256, 0);
        if (e != hipSuccess || nb < 1) nb = 2;
        int gsz = nb * 256;                 // MI355X: 256 CUs
        if (gsz > 1792) gsz = 1792;
        g_grid = gsz;
    }

    void* args[] = {
        (void*)&x, (void*)&w1, (void*)&b1, (void*)&g1, (void*)&be1,
        (void*)&w2, (void*)&b2, (void*)&g2, (void*)&be2,
        (void*)&fcw, (void*)&fcb,
        (void*)&mm, (void*)&y2, (void*)&stats, (void*)&out
    };
    hipLaunchCooperativeKernel(fused_all_k, dim3(g_grid), dim3(256),
                               args, 0, stream);
}

// Round 9
// 226.075 us; speedup vs baseline: 2.2940x; 2.2940x over previous
//
#include <hip/hip_runtime.h>
#include <math.h>

typedef float v2f __attribute__((ext_vector_type(2)));

#define BATCH 128
#define CIN 3
#define H 224
#define W 224
#define C1 16
#define HP 56
#define WP 56
#define C2 32
#define H2 28
#define W2 28

#define TROWS 17               // input rows per conv1 strip (4 pooled rows + halo)
#define CHF (TROWS * W)        // 3808 floats per channel chunk
#define CHB (CHF * 4)          // 15232 bytes per channel chunk

// ---------------------------------------------------------------------------
// conv1 (s2,p1) + stats + 2x2 pool(max,min), SINGLE PASS.
// R14 = R11 (best measured: 65us prof, e2e 219.8) + packed-FP32 FMA.
// Quadrant pairs (q0,q1) and (q2,q3) share weights and use shifted inputs:
// pv[kw] = {p[kw], p[kw+2]} feeds one v_pk_fma_f32 for both halves.
// FMA insts 1728 -> 864 per thread; VALUBusy was 51% -> VALU issue is the
// largest attackable term (R11 PMC). Same arithmetic order per element ->
// bitwise-identical output; if backend doesn't pack, this IS R11 (safe).
// R13 cooperative fusion reverted: 676us kernel, falsified launch-overhead
// theory (e2e ~= kernel time).
// ---------------------------------------------------------------------------
__global__ __launch_bounds__(256) void conv1_fused_k(
    const float* __restrict__ x, const float* __restrict__ w1,
    const float* __restrict__ b1, float2* __restrict__ mm,
    float* __restrict__ s_sum, float* __restrict__ s_sq)
{
    __shared__ __align__(16) float tile[3 * CHF];   // 45,696 B
    __shared__ float red[4][16], redq[4][16];

    const int tid = threadIdx.x;
    const int wave = tid >> 6, lane = tid & 63;
    const int bid = blockIdx.x;             // 0..1791
    const int n = bid / 14;
    const int g = bid % 14;                 // pooled-row group (4 rows)
    const int ph = g * 4 + wave;            // this wave's pooled row
    const int pw = (lane < 56) ? lane : 55; // clamp idle lanes (masked later)
    const bool active = lane < 56;
    const bool topok = ph > 0;
    const bool pwok  = pw > 0;

    // ---- fill: async global->LDS, 16B/lane wave ops (R11-proven) ----
    const int startrow = (g == 0) ? 0 : (16 * g - 1);
    const int nops     = (g == 0) ? 14 : 15;      // 1024B ops per channel
    const int base_off = (g == 0) ? (W * 4) : 0;  // row -1 slot skipped
#pragma unroll
    for (int ci = 0; ci < CIN; ++ci) {
        const char* gch = (const char*)(x + ((size_t)n * CIN + ci) * (H * W)
                                        + (size_t)startrow * W);
        char* lch = (char*)tile + ci * CHB + base_off;
        for (int kp = wave; kp < nops; kp += 4) {
            int off = kp * 1024;
            if (off > 14208) off = 14208;   // exact-coverage clamp, no overread
            __builtin_amdgcn_global_load_lds(
                (const __attribute__((address_space(1))) void*)(gch + off + lane * 16),
                (__attribute__((address_space(3))) void*)(lch + off),
                16, 0, 0);
        }
    }

    v2f accQ01[16], accQ23[16];             // {q0,q1} and {q2,q3} per channel
#pragma unroll
    for (int j = 0; j < 16; ++j) {
        const float bb = b1[j];
        accQ01[j] = (v2f){bb, bb};
        accQ23[j] = (v2f){bb, bb};
    }

    __syncthreads();   // drains vmcnt(0): all LDS writes landed

    // ---- compute: LDS reads + packed FMA burst ----
#pragma unroll
    for (int ci = 0; ci < CIN; ++ci) {
#pragma unroll
        for (int l = 0; l < 5; ++l) {
            const int tr = 4 * wave + l;    // tile row (0..16)
            const float* rp = tile + ci * CHF + tr * W;
            const float4 fa = *(const float4*)(rp + 4 * pw);
            const float4 fb = *(const float4*)(rp + max(4 * pw - 4, 0));
            const bool rok = (l > 0) || topok;
            const float p0 = (rok && pwok) ? fb.w : 0.0f;
            const float p1 = rok ? fa.x : 0.0f;
            const float p2 = rok ? fa.y : 0.0f;
            const float p3 = rok ? fa.z : 0.0f;
            const float p4 = rok ? fa.w : 0.0f;
            // packed input pairs: one pk-fma covers both quadrant halves
            const v2f pv0 = (v2f){p0, p2};
            const v2f pv1 = (v2f){p1, p3};
            const v2f pv2 = (v2f){p2, p4};
#pragma unroll
            for (int j = 0; j < 16; ++j) {
                const float* wc = w1 + (j * CIN + ci) * 9;  // uniform->SGPR
                if (l < 3) {
                    const float wa = wc[l * 3 + 0];
                    const float wb = wc[l * 3 + 1];
                    const float wd = wc[l * 3 + 2];
                    accQ01[j] += wa * pv0 + wb * pv1 + wd * pv2;
                }
                if (l >= 2) {
                    const int kh = l - 2;
                    const float wa = wc[kh * 3 + 0];
                    const float wb = wc[kh * 3 + 1];
                    const float wd = wc[kh * 3 + 2];
                    accQ23[j] += wa * pv0 + wb * pv1 + wd * pv2;
                }
            }
        }
    }

    // ---- store mm + per-channel stats ----
#pragma unroll
    for (int j = 0; j < 16; ++j) {
        const float a0 = accQ01[j].x, a1 = accQ01[j].y;
        const float a2 = accQ23[j].x, a3 = accQ23[j].y;
        if (active) {
            const int o = (n * C1 + j) * (HP * WP) + ph * WP + pw;
            mm[o] = make_float2(fmaxf(fmaxf(a0, a1), fmaxf(a2, a3)),
                                fminf(fminf(a0, a1), fminf(a2, a3)));
        }
        float s = active ? (a0 + a1 + a2 + a3) : 0.0f;
        float q = active ? (a0 * a0 + a1 * a1 + a2 * a2 + a3 * a3) : 0.0f;
#pragma unroll
        for (int off = 32; off > 0; off >>= 1) {
            s += __shfl_xor(s, off);
            q += __shfl_xor(q, off);
        }
        if (lane == 0) { red[wave][j] = s; redq[wave][j] = q; }
    }
    __syncthreads();
    if (tid < 16) {
        atomicAdd(&s_sum[tid],
                  red[0][tid] + red[1][tid] + red[2][tid] + red[3][tid]);
    } else if (tid < 32) {
        const int j = tid - 16;
        atomicAdd(&s_sq[j],
                  redq[0][j] + redq[1][j] + redq[2][j] + redq[3][j]);
    }
}

// ---------------------------------------------------------------------------
// conv2 (s2,p1) + stats; BN1 finalize folded in.
// R14 = R9 (proven) + packed-FP32 FMA: output pair (A,B) shares weights,
// hv[kh][kw] = {h[kw], h[kw+2]} -> FMA insts 2304 -> 1152 per thread.
// Thread = TWO horizontally-adjacent outputs x 8 channels. Grid (196, 4).
// ---------------------------------------------------------------------------
__global__ __launch_bounds__(256) void conv2_k(
    const float2* __restrict__ mm,
    const float* __restrict__ s1sum, const float* __restrict__ s1sq,
    const float* __restrict__ g1, const float* __restrict__ be1,
    const float* __restrict__ w2, const float* __restrict__ b2,
    float* __restrict__ y2,
    float* __restrict__ s_sum, float* __restrict__ s_sq)
{
    __shared__ float red[4][8], redq[4][8];
    const int tid = threadIdx.x;
    const int t = blockIdx.x * 256 + tid;   // 0..50175
    const int c0 = blockIdx.y * 8;
    const int n = t / 392;                  // image
    const int r = t % 392;                  // 28 rows x 14 col-pairs
    const int oh = r / 14;
    const int ow = (r % 14) * 2;            // even; outputs ow, ow+1
    const bool topok = oh > 0;
    const bool owok  = ow > 0;
    const float inv1 = 1.0f / (float)(BATCH * 112 * 112);

    v2f accAB[8];                           // {outA, outB} per channel
#pragma unroll
    for (int c = 0; c < 8; ++c) {
        const float bb = b2[c0 + c];
        accAB[c] = (v2f){bb, bb};
    }

#pragma unroll 2
    for (int ci = 0; ci < C1; ++ci) {
        const float mean = s1sum[ci] * inv1;
        const float var  = s1sq[ci] * inv1 - mean * mean;
        const float s1 = g1[ci] * rsqrtf(var + 1e-5f);
        const float t1 = be1[ci] - mean * s1;

        const float2* pl = mm + (n * C1 + ci) * (HP * WP);

        float4 fa[3], fb[3];
        float2 lpv[3];
#pragma unroll
        for (int kh = 0; kh < 3; ++kh) {
            const int ih = max(2 * oh - 1 + kh, 0);
            const float2* rowp = pl + ih * WP;
            fa[kh]  = *(const float4*)(rowp + 2 * ow);
            fb[kh]  = *(const float4*)(rowp + 2 * ow + 2);
            lpv[kh] = rowp[max(2 * ow - 1, 0)];
        }

        // BN1+ReLU per pooled unit, packed as {unit kw, unit kw+2}
        v2f hv[3][3];
#pragma unroll
        for (int kh = 0; kh < 3; ++kh) {
            const bool rok = (kh > 0) || topok;
            const float u0 = fmaxf(0.0f, fmaxf(s1 * lpv[kh].x + t1, s1 * lpv[kh].y + t1));
            const float u1 = fmaxf(0.0f, fmaxf(s1 * fa[kh].x + t1, s1 * fa[kh].y + t1));
            const float u2 = fmaxf(0.0f, fmaxf(s1 * fa[kh].z + t1, s1 * fa[kh].w + t1));
            const float u3 = fmaxf(0.0f, fmaxf(s1 * fb[kh].x + t1, s1 * fb[kh].y + t1));
            const float u4 = fmaxf(0.0f, fmaxf(s1 * fb[kh].z + t1, s1 * fb[kh].w + t1));
            const float h0 = (rok && owok) ? u0 : 0.0f;
            const float h1 = rok ? u1 : 0.0f;
            const float h2 = rok ? u2 : 0.0f;
            const float h3 = rok ? u3 : 0.0f;
            const float h4 = rok ? u4 : 0.0f;
            hv[kh][0] = (v2f){h0, h2};
            hv[kh][1] = (v2f){h1, h3};
            hv[kh][2] = (v2f){h2, h4};
        }

#pragma unroll
        for (int c = 0; c < 8; ++c) {
            const float* wc = w2 + ((c0 + c) * C1 + ci) * 9;   // uniform
            v2f a = accAB[c];
#pragma unroll
            for (int kh = 0; kh < 3; ++kh) {
                const float w0 = wc[kh * 3 + 0];
                const float w1v = wc[kh * 3 + 1];
                const float w2v = wc[kh * 3 + 2];
                a += w0 * hv[kh][0] + w1v * hv[kh][1] + w2v * hv[kh][2];
            }
            accAB[c] = a;
        }
    }

#pragma unroll
    for (int c = 0; c < 8; ++c) {
        const float aA = accAB[c].x, aB = accAB[c].y;
        const int p = oh * W2 + ow;
        *(float2*)(y2 + (n * C2 + c0 + c) * (H2 * W2) + p) = make_float2(aA, aB);
        float s = aA + aB, q = aA * aA + aB * aB;
#pragma unroll
        for (int off = 32; off > 0; off >>= 1) {
            s += __shfl_xor(s, off);
            q += __shfl_xor(q, off);
        }
        if ((tid & 63) == 0) { red[tid >> 6][c] = s; redq[tid >> 6][c] = q; }
    }
    __syncthreads();
    if (tid < 8) {
        atomicAdd(&s_sum[c0 + tid],
                  red[0][tid] + red[1][tid] + red[2][tid] + red[3][tid]);
    } else if (tid < 16) {
        const int c = tid - 8;
        atomicAdd(&s_sq[c0 + c],
                  redq[0][c] + redq[1][c] + redq[2][c] + redq[3][c]);
    }
}

// ---------------------------------------------------------------------------
// head fused: BN2 finalize + ReLU + avgpool + FC + cos, one block per image.
// UNCHANGED (control).
// ---------------------------------------------------------------------------
__global__ __launch_bounds__(256) void head_fused_k(
    const float* __restrict__ y2,
    const float* __restrict__ s2sum, const float* __restrict__ s2sq,
    const float* __restrict__ g2, const float* __restrict__ be2,
    const float* __restrict__ fcw, const float* __restrict__ fcb,
    float* __restrict__ out)
{
    __shared__ float feat[C2];
    const int n = blockIdx.x;
    const int tid = threadIdx.x;
    const int wave = tid >> 6, lane = tid & 63;
    const float inv2 = 1.0f / (float)(BATCH * H2 * W2);
#pragma unroll
    for (int k = 0; k < 8; ++k) {
        const int c = wave * 8 + k;
        const float mean = s2sum[c] * inv2;
        const float var  = s2sq[c] * inv2 - mean * mean;
        const float s = g2[c] * rsqrtf(var + 1e-5f);
        const float t = be2[c] - mean * s;
        const float4* yp = (const float4*)(y2 + (n * C2 + c) * (H2 * W2));
        float a = 0.0f;
        for (int i = lane; i < 196; i += 64) {
            const float4 v = yp[i];
            a += fmaxf(0.0f, s * v.x + t) + fmaxf(0.0f, s * v.y + t)
               + fmaxf(0.0f, s * v.z + t) + fmaxf(0.0f, s * v.w + t);
        }
#pragma unroll
        for (int off = 32; off > 0; off >>= 1) a += __shfl_xor(a, off);
        if (lane == 0) feat[c] = a * (1.0f / (H2 * W2));
    }
    __syncthreads();
    if (tid == 0) {
        float logit = fcb[0];
#pragma unroll
        for (int c = 0; c < C2; ++c) logit += feat[c] * fcw[c];
        const float pc = cosf(logit);
        out[2 * n]     = pc;
        out[2 * n + 1] = 1.0f - pc;
    }
}

extern "C" void kernel_launch(void* const* d_in, const int* in_sizes, int n_in,
                              void* d_out, int out_size, void* d_ws, size_t ws_size,
                              hipStream_t stream) {
    const float* x   = (const float*)d_in[0];
    const float* w1  = (const float*)d_in[1];
    const float* b1  = (const float*)d_in[2];
    const float* g1  = (const float*)d_in[3];
    const float* be1 = (const float*)d_in[4];
    const float* w2  = (const float*)d_in[5];
    const float* b2  = (const float*)d_in[6];
    const float* g2  = (const float*)d_in[7];
    const float* be2 = (const float*)d_in[8];
    const float* fcw = (const float*)d_in[9];
    const float* fcb = (const float*)d_in[10];
    float* out = (float*)d_out;

    float* ws = (float*)d_ws;
    float2* mm = (float2*)ws;                              // 6,422,528 float2
    float* y2 = ws + (size_t)2 * BATCH * C1 * HP * WP;     // 3,211,264 floats
    float* stats = y2 + (size_t)BATCH * C2 * H2 * W2;
    float* s1sum = stats;          // 16
    float* s1sq  = stats + 16;     // 16
    float* s2sum = stats + 32;     // 32
    float* s2sq  = stats + 64;     // 32
    // ws use ~64.3 MB (proven safe)

    hipMemsetAsync(stats, 0, 96 * sizeof(float), stream);

    conv1_fused_k<<<dim3(1792), 256, 0, stream>>>(x, w1, b1, mm, s1sum, s1sq);
    conv2_k<<<dim3(196, 4), 256, 0, stream>>>(mm, s1sum, s1sq, g1, be1,
                                              w2, b2, y2, s2sum, s2sq);
    head_fused_k<<<BATCH, 256, 0, stream>>>(y2, s2sum, s2sq, g2, be2,
                                            fcw, fcb, out);
}